// Round 8
// baseline (539.345 us; speedup 1.0000x reference)
//
#include <hip/hip_runtime.h>
#include <hip/hip_fp16.h>

// Problem: B=4, S=2048, H=8, E=64. BH=32 heads total.
// R16: 2 independent blocks per CU to fill the 20% non-VALU-busy gap.
//      attn restructured: 512 blocks x 512 threads (8 waves), 128 Q-rows per
//      block, KVBLK=32 (kt 0..63). LDS 55KB/block -> 2 blocks/CU with
//      INDEPENDENT barriers (cross-block VALU fills barrier skew / MFMA
//      stalls — the m114 co-schedule effect, unavailable at 1 block/CU).
//      All per-element float ops, accumulation orders, and threefry counters
//      bit-identical to R8/R14 (col-group sequence preserved; mask macro
//      re-paired (n=0,r)/(n=1,r) with b1=a1+16, per-chain math untouched).
//      Proj: R14 merged 1536-block kernel, unchanged.
// Workspace: Qh 0, Ql 8M, Kh 16M, Kl 24M, Vth 32M, Vtl 40M  (48 MiB)

typedef _Float16 f16;
typedef _Float16 f16x4 __attribute__((ext_vector_type(4)));
typedef _Float16 f16x8 __attribute__((ext_vector_type(8)));
typedef float f32x4v __attribute__((ext_vector_type(4)));
typedef unsigned int u32;
typedef unsigned short u16;

// ---------------- threefry2x32 (jax partitionable), key (0,42) — 2-chain ----------------
// per flat i over [B,H,S,S]: (b1,b2)=threefry2x32((0,42),(0,i)); keep <=> (b1^b2) < 0xE6666600
#define QR2(r) \
    a0 += a1; b0 += b1; \
    a1 = __builtin_rotateleft32(a1, r); b1 = __builtin_rotateleft32(b1, r); \
    a1 ^= a0; b1 ^= b0;
#define TF4(p,q,rr,s) QR2(p) QR2(q) QR2(rr) QR2(s)
#define TF_FULL \
    TF4(13,15,26,6)   a0 += 42u;          a1 += 0x1BD11BF1u;  b0 += 42u;          b1 += 0x1BD11BF1u; \
    TF4(17,29,16,24)  a0 += 0x1BD11BF0u;  a1 += 2u;           b0 += 0x1BD11BF0u;  b1 += 2u; \
    TF4(13,15,26,6)                       a1 += 45u;                              b1 += 45u; \
    TF4(17,29,16,24)  a0 += 42u;          a1 += 0x1BD11BF4u;  b0 += 42u;          b1 += 0x1BD11BF4u; \
    TF4(13,15,26,6)   a0 += 0x1BD11BF0u;  a1 += 5u;           b0 += 0x1BD11BF0u;  b1 += 5u;

// 8 PRIVATE mask bits for this thread's elements in one 32-col kt tile:
// rows qt*128 + w*16 + kg*4 + r (r=0..3), cols kt*32 + n*16 + lrow (n=0..1).
// bit index = n*4 + r. Chain a: (n=0, r=j_) -> bit j_; chain b: (n=1, r=j_)
// (col +16) -> bit j_+4. Per-element counters identical to the 64-col version.
#define MASK8(ktArg, dst) do { \
    u32 wm_ = 0u; \
    const u32 cb_ = ((u32)(bh * 2048 + qt * 128 + w * 16 + kg * 4) << 11) \
                  + (u32)(ktArg) * 32u + (u32)lrow + 42u; \
    _Pragma("unroll") \
    for (int j_ = 0; j_ < 4; ++j_) { \
        u32 a0 = 0u, a1 = cb_ + (u32)(j_ * 2048); \
        u32 b0 = 0u, b1 = a1 + 16u; \
        TF_FULL \
        wm_ |= ((a0 ^ a1) < 0xE6666600u) ? (1u << j_) : 0u; \
        wm_ |= ((b0 ^ b1) < 0xE6666600u) ? (1u << (j_ + 4)) : 0u; \
    } \
    (dst) = wm_; \
} while (0)

// ---------------- merged projection kernel: 1536 blocks x 256 threads ----------------
__global__ __launch_bounds__(256) void proj_all_kernel(
    const float* __restrict__ Xq, const float* __restrict__ Xk, const float* __restrict__ Xv,
    const float* __restrict__ Wq, const float* __restrict__ Wk, const float* __restrict__ Wv,
    const float* __restrict__ bq, const float* __restrict__ bk, const float* __restrict__ bv,
    f16* __restrict__ Qh, f16* __restrict__ Ql,
    f16* __restrict__ Kh, f16* __restrict__ Kl,
    f16* __restrict__ Vth, f16* __restrict__ Vtl)
{
    __shared__ __align__(16) float Wl[64 * 68];
    __shared__ __align__(16) float Xl[128 * 68];   // V path reuses as Th/Tl after compute
    const int t = threadIdx.x;
    const int blk = blockIdx.x;

    const int tx = t & 15;
    const int ty = t >> 4;
    const int f0 = ty * 4;

    if (blk < 1024) {
        const int isK = blk >> 9;
        const float* X    = isK ? Xk : Xq;
        const float* W    = isK ? Wk : Wq;
        const float* bias = isK ? bk : bq;
        f16* Oh = isK ? Kh : Qh;
        f16* Ol = isK ? Kl : Ql;
        const int tb = (blk & 511) * 128;

        for (int c = t; c < 1024; c += 256) {
            int f = c >> 4, e4 = (c & 15) << 2;
            *(float4*)&Wl[f * 68 + e4] = *(const float4*)(W + f * 64 + e4);
        }
        for (int c = t; c < 2048; c += 256) {
            int tok = c >> 4, e4 = (c & 15) << 2;
            *(float4*)&Xl[tok * 68 + e4] = *(const float4*)(X + (size_t)(tb + tok) * 64 + e4);
        }
        __syncthreads();

        float acc[8][4];
#pragma unroll
        for (int i = 0; i < 8; ++i)
#pragma unroll
            for (int j = 0; j < 4; ++j) acc[i][j] = bias[f0 + j];

        for (int e = 0; e < 64; e += 4) {
            float4 wv[4];
#pragma unroll
            for (int j = 0; j < 4; ++j) wv[j] = *(float4*)&Wl[(f0 + j) * 68 + e];
#pragma unroll
            for (int i = 0; i < 8; ++i) {
                float4 xv = *(float4*)&Xl[(tx + 16 * i) * 68 + e];
#pragma unroll
                for (int j = 0; j < 4; ++j)
                    acc[i][j] += xv.x * wv[j].x + xv.y * wv[j].y + xv.z * wv[j].z + xv.w * wv[j].w;
            }
        }

#pragma unroll
        for (int i = 0; i < 8; ++i) {
            int tin = tb + tx + 16 * i;
            int h  = tin & 7;
            int bs = tin >> 3;
            int b  = bs >> 11;
            int s  = bs & 2047;
            size_t o = ((size_t)(b * 8 + h) * 2048 + s) * 64 + f0;
            f16x4 hv, lv;
#pragma unroll
            for (int j = 0; j < 4; ++j) {
                float a = acc[i][j];
                f16 hh = (f16)a;
                hv[j] = hh;
                lv[j] = (f16)(a - (float)hh);
            }
            *(f16x4*)(Oh + o) = hv;
            *(f16x4*)(Ol + o) = lv;
        }
    } else {
        const int vx = blk - 1024;
        const int sc0 = (vx & 15) * 128;
        const int bh = vx >> 4, b = bh >> 3, h = bh & 7;

        for (int c = t; c < 1024; c += 256) {
            int f = c >> 4, e4 = (c & 15) << 2;
            *(float4*)&Wl[f * 68 + e4] = *(const float4*)(Wv + f * 64 + e4);
        }
        for (int c = t; c < 2048; c += 256) {
            int tok = c >> 4, e4 = (c & 15) << 2;
            size_t src = ((size_t)(b * 2048 + sc0 + tok) * 8 + h) * 64 + e4;
            *(float4*)&Xl[tok * 68 + e4] = *(const float4*)(Xv + src);
        }
        __syncthreads();

        float acc[8][4];
#pragma unroll
        for (int i = 0; i < 8; ++i)
#pragma unroll
            for (int j = 0; j < 4; ++j) acc[i][j] = bv[f0 + j];

        for (int e = 0; e < 64; e += 4) {
            float4 wv[4];
#pragma unroll
            for (int j = 0; j < 4; ++j) wv[j] = *(float4*)&Wl[(f0 + j) * 68 + e];
#pragma unroll
            for (int i = 0; i < 8; ++i) {
                float4 xv = *(float4*)&Xl[(tx + 16 * i) * 68 + e];
#pragma unroll
                for (int j = 0; j < 4; ++j)
                    acc[i][j] += xv.x * wv[j].x + xv.y * wv[j].y + xv.z * wv[j].z + xv.w * wv[j].w;
            }
        }
        __syncthreads();

        f16* Th = (f16*)Xl;            // [64 f][136 s]
        f16* Tl = Th + 64 * 136;
#pragma unroll
        for (int i = 0; i < 8; ++i) {
            int s = tx + 16 * i;
#pragma unroll
            for (int j = 0; j < 4; ++j) {
                float a = acc[i][j];
                f16 hh = (f16)a;
                Th[(f0 + j) * 136 + s] = hh;
                Tl[(f0 + j) * 136 + s] = (f16)(a - (float)hh);
            }
        }
        __syncthreads();

        for (int c = t; c < 1024; c += 256) {
            int e = c >> 4, sc = (c & 15) << 3;
            size_t o = ((size_t)bh * 64 + e) * 2048 + sc0 + sc;
            *(uint4*)(Vth + o) = *(uint4*)&Th[e * 136 + sc];
            *(uint4*)(Vtl + o) = *(uint4*)&Tl[e * 136 + sc];
        }
    }
}

// identical score computation for both passes (bit-identical chain order per element)
// 32-col tile: n = 0..1. Same per-S[n] MFMA chain as the 64-col version.
#define COMPUTE_S2(S, khp, klp) do { \
    _Pragma("unroll") for (int n = 0; n < 2; ++n) S[n] = f32x4v{0.f,0.f,0.f,0.f}; \
    _Pragma("unroll") for (int n = 0; n < 2; ++n) { \
        _Pragma("unroll") for (int ks = 0; ks < 2; ++ks) { \
            const int off_ = (n * 16 + lrow) * LDK + ks * 32 + kg * 8; \
            f16x8 bhf_ = *(const f16x8*)&(khp)[off_]; \
            f16x8 blf_ = *(const f16x8*)&(klp)[off_]; \
            S[n] = __builtin_amdgcn_mfma_f32_16x16x32_f16(qh[ks], bhf_, S[n], 0, 0, 0); \
            S[n] = __builtin_amdgcn_mfma_f32_16x16x32_f16(ql[ks], bhf_, S[n], 0, 0, 0); \
            S[n] = __builtin_amdgcn_mfma_f32_16x16x32_f16(qh[ks], blf_, S[n], 0, 0, 0); \
        } \
    } } while (0)

// grid (16, 32): x = 128-row Q tile, y = bh. 8 waves x 16 rows. 2 blocks/CU.
// KVBLK=32, kt = 0..63. MFMA 16x16x32 f16.
// A: A[m=lane&15][k=(lane>>4)*8+j]; B: B[k][n=lane&15]; C: row=(lane>>4)*4+r, col=lane&15.
__global__ __launch_bounds__(512, 4) void attn_kernel(
    const f16* __restrict__ Qh, const f16* __restrict__ Ql,
    const f16* __restrict__ Kh, const f16* __restrict__ Kl,
    const f16* __restrict__ Vth, const f16* __restrict__ Vtl,
    float* __restrict__ out)
{
    constexpr int LDK = 88;   // K token-rows: 64 dims + pad (176 B, 16B-aligned)
    constexpr int LDV = 40;   // V e-rows: 32 s + pad (80 B, 16B-aligned)
    constexpr int PLD = 48;   // p_l rows: 32 cols + pad (96 B, 16B-aligned)
    __shared__ __align__(16) f16 kh_l[2][32 * LDK];   // double-buffered K tile
    __shared__ __align__(16) f16 kl_l[2][32 * LDK];
    __shared__ __align__(16) f16 vh_l[2][64 * LDV];   // [e][s] V tile
    __shared__ __align__(16) f16 vl_l[2][64 * LDV];
    __shared__ __align__(16) f16 p_l[8][16 * PLD];    // per-wave P tile (16 rows x 32 cols)

    const int t = threadIdx.x;
    const int w = t >> 6;               // 0..7
    const int lane = t & 63;
    const int lrow = lane & 15;
    const int kg = lane >> 4;
    const int qt = blockIdx.x;          // 0..15
    const int bh = blockIdx.y;

    // staging roles: threads 0..255 -> K, 256..511 -> V. One uint4 pair each.
    const int sc  = t & 255;
    const int sxk = sc >> 3;            // K token-row in tile (0..31)
    const int sck = (sc & 7) << 3;      // dim offset (0..56)
    const int sxv = sc >> 2;            // V e-row (0..63)
    const int scv = (sc & 3) << 3;      // s offset in tile (0..24)
    const bool isK = (t < 256);

    // persistent Q fragments (hi/lo), one 16-row m-tile per wave, 2 k-steps
    f16x8 qh[2], ql[2];
    {
        size_t rowg = (size_t)bh * 2048 + qt * 128 + w * 16 + lrow;
        const f16* ph = Qh + rowg * 64 + kg * 8;
        const f16* pl = Ql + rowg * 64 + kg * 8;
        qh[0] = *(const f16x8*)(ph);
        qh[1] = *(const f16x8*)(ph + 32);
        ql[0] = *(const f16x8*)(pl);
        ql[1] = *(const f16x8*)(pl + 32);
    }

    const size_t kbase = (size_t)bh * 2048 * 64;   // same footprint for K and Vt

    // ---- pass A: row sums l = sum exp(s - 8); K only, double-buffered ----
    float lsum[4] = {0.f, 0.f, 0.f, 0.f};
    if (isK) {      // prologue: stage kt=0 into buf 0
        size_t g = kbase + (size_t)(sxk * 64) + sck;
        uint4 h4 = *(const uint4*)(Kh + g);
        uint4 l4 = *(const uint4*)(Kl + g);
        *(uint4*)&kh_l[0][sxk * LDK + sck] = h4;
        *(uint4*)&kl_l[0][sxk * LDK + sck] = l4;
    }
    __syncthreads();

    for (int kt = 0; kt < 64; ++kt) {
        const int cur = kt & 1;
        uint4 sA, sB;
        if (isK && kt < 63) {           // issue next tile's loads early
            size_t g = kbase + (size_t)((kt + 1) * 32 + sxk) * 64 + sck;
            sA = *(const uint4*)(Kh + g);
            sB = *(const uint4*)(Kl + g);
        }
        f32x4v sfr[2];
        COMPUTE_S2(sfr, kh_l[cur], kl_l[cur]);
#pragma unroll
        for (int n = 0; n < 2; ++n)
#pragma unroll
            for (int r = 0; r < 4; ++r)
                lsum[r] += __expf(fmaf(sfr[n][r], 0.125f, -8.0f));
        if (isK && kt < 63) {           // commit after compute
            *(uint4*)&kh_l[cur ^ 1][sxk * LDK + sck] = sA;
            *(uint4*)&kl_l[cur ^ 1][sxk * LDK + sck] = sB;
        }
        __syncthreads();                // single barrier per kt (8 waves)
    }

    float rsc[4];
#pragma unroll
    for (int r = 0; r < 4; ++r) {
        float v = lsum[r];
        v += __shfl_xor(v, 1);
        v += __shfl_xor(v, 2);
        v += __shfl_xor(v, 4);
        v += __shfl_xor(v, 8);
        rsc[r] = 1.0f / (0.9f * v);   // folds dropout 1/(1-p)
    }

    // ---- pass B: recompute s, exact p, PRIVATE threefry dropout, fp16 cast, PV ----
    f32x4v oacc[4];
#pragma unroll
    for (int fn = 0; fn < 4; ++fn) oacc[fn] = f32x4v{0.f, 0.f, 0.f, 0.f};

    {   // prologue: stage kt=0 (K and V) into buf 0
        if (isK) {
            size_t g = kbase + (size_t)(sxk * 64) + sck;
            uint4 h4 = *(const uint4*)(Kh + g);
            uint4 l4 = *(const uint4*)(Kl + g);
            *(uint4*)&kh_l[0][sxk * LDK + sck] = h4;
            *(uint4*)&kl_l[0][sxk * LDK + sck] = l4;
        } else {
            size_t g = kbase + (size_t)sxv * 2048 + scv;
            uint4 h4 = *(const uint4*)(Vth + g);
            uint4 l4 = *(const uint4*)(Vtl + g);
            *(uint4*)&vh_l[0][sxv * LDV + scv] = h4;
            *(uint4*)&vl_l[0][sxv * LDV + scv] = l4;
        }
    }
    __syncthreads();

    for (int kt = 0; kt < 64; ++kt) {
        const int cur = kt & 1;
        uint4 sA, sB;
        if (kt < 63) {                  // issue next tile's loads early
            if (isK) {
                size_t g = kbase + (size_t)((kt + 1) * 32 + sxk) * 64 + sck;
                sA = *(const uint4*)(Kh + g);
                sB = *(const uint4*)(Kl + g);
            } else {
                size_t g = kbase + (size_t)sxv * 2048 + (kt + 1) * 32 + scv;
                sA = *(const uint4*)(Vth + g);
                sB = *(const uint4*)(Vtl + g);
            }
        }

        u32 pm;
        MASK8(kt, pm);                  // thread-private threefry (pure VALU)

        f32x4v sfr[2];
        COMPUTE_S2(sfr, kh_l[cur], kl_l[cur]);

#pragma unroll
        for (int n = 0; n < 2; ++n)
#pragma unroll
            for (int r = 0; r < 4; ++r) {
                float e = __expf(fmaf(sfr[n][r], 0.125f, -8.0f));
                float p = e * rsc[r];
                if (!((pm >> (n * 4 + r)) & 1u)) p = 0.0f;
                p_l[w][(kg * 4 + r) * PLD + n * 16 + lrow] = (f16)p;  // RTNE = astype(f16)
            }

        // PV: out += P(16f exact) * (Vh + Vl)   (wave-private p_l: no barrier)
        // one MFMA consumes the whole 32-col tile (k=32)
        {
            f16x8 pa0 = *(const f16x8*)&p_l[w][lrow * PLD + kg * 8];
#pragma unroll
            for (int fn = 0; fn < 4; ++fn) {
                const int voff = (fn * 16 + lrow) * LDV + kg * 8;
                f16x8 vhf = *(const f16x8*)&vh_l[cur][voff];
                f16x8 vlf = *(const f16x8*)&vl_l[cur][voff];
                oacc[fn] = __builtin_amdgcn_mfma_f32_16x16x32_f16(pa0, vhf, oacc[fn], 0, 0, 0);
                oacc[fn] = __builtin_amdgcn_mfma_f32_16x16x32_f16(pa0, vlf, oacc[fn], 0, 0, 0);
            }
        }

        if (kt < 63) {                  // commit after compute
            if (isK) {
                *(uint4*)&kh_l[cur ^ 1][sxk * LDK + sck] = sA;
                *(uint4*)&kl_l[cur ^ 1][sxk * LDK + sck] = sB;
            } else {
                *(uint4*)&vh_l[cur ^ 1][sxv * LDV + scv] = sA;
                *(uint4*)&vl_l[cur ^ 1][sxv * LDV + scv] = sB;
            }
        }
        __syncthreads();                // single barrier per kt (8 waves)
    }

    // epilogue: out [b,h,s,e] fp32
#pragma unroll
    for (int fn = 0; fn < 4; ++fn)
#pragma unroll
        for (int r = 0; r < 4; ++r) {
            int row = qt * 128 + w * 16 + kg * 4 + r;
            out[((size_t)bh * 2048 + row) * 64 + fn * 16 + lrow] = oacc[fn][r];
        }
}

extern "C" void kernel_launch(void* const* d_in, const int* in_sizes, int n_in,
                              void* d_out, int out_size, void* d_ws, size_t ws_size,
                              hipStream_t stream) {
    (void)in_sizes; (void)n_in; (void)out_size; (void)ws_size;
    const float* query = (const float*)d_in[0];
    const float* key_  = (const float*)d_in[1];
    const float* value = (const float*)d_in[2];
    const float* Wq = (const float*)d_in[3];
    const float* bq = (const float*)d_in[4];
    const float* Wk = (const float*)d_in[5];
    const float* bk = (const float*)d_in[6];
    const float* Wv = (const float*)d_in[7];
    const float* bv = (const float*)d_in[8];

    char* ws = (char*)d_ws;                 // needs 48 MiB
    f16* Qh  = (f16*)(ws);
    f16* Ql  = (f16*)(ws + 8388608);
    f16* Kh  = (f16*)(ws + 16777216);
    f16* Kl  = (f16*)(ws + 25165824);
    f16* Vth = (f16*)(ws + 33554432);
    f16* Vtl = (f16*)(ws + 41943040);

    proj_all_kernel<<<1536, 256, 0, stream>>>(
        query, key_, value, Wq, Wk, Wv, bq, bk, bv,
        Qh, Ql, Kh, Kl, Vth, Vtl);
    attn_kernel<<<dim3(16, 32), 512, 0, stream>>>(Qh, Ql, Kh, Kl, Vth, Vtl, (float*)d_out);
}

// Round 10
// 471.332 us; speedup vs baseline: 1.1443x; 1.1443x over previous
//
#include <hip/hip_runtime.h>
#include <hip/hip_fp16.h>

// Problem: B=4, S=2048, H=8, E=64. BH=32 heads total.
// R17b: RESUBMISSION of R17 (round-9 bench failed on container acquisition,
//       not kernel error). Recombination of best-measured components:
//  - attn: VERBATIM R15 (394.3us measured): R8 structure, mask fused in pass B
//    (2-chain MASK16 — placement/ILP insensitive per R9-R13), p_l at PLD=68.
//    R16's 2-block/CU restructure regressed (477us): per-tile fixed costs
//    doubled. attn floor is confirmed at ~394us / 80% VALUBusy.
//  - proj: VERBATIM R12 config — merged Q+K 1024-block kernel + separate
//    proj_v. Measured proj region 70.2us vs 84-87us for the R14 1536-block
//    merge (V-branch divergence regressed it). Best measured proj config.
// Workspace: Qh 0, Ql 8M, Kh 16M, Kl 24M, Vth 32M, Vtl 40M  (48 MiB)

typedef _Float16 f16;
typedef _Float16 f16x4 __attribute__((ext_vector_type(4)));
typedef _Float16 f16x8 __attribute__((ext_vector_type(8)));
typedef float f32x4v __attribute__((ext_vector_type(4)));
typedef unsigned int u32;
typedef unsigned short u16;

// ---------------- threefry2x32 (jax partitionable), key (0,42) — 2-chain ----------------
// per flat i over [B,H,S,S]: (b1,b2)=threefry2x32((0,42),(0,i)); keep <=> (b1^b2) < 0xE6666600
#define QR2(r) \
    a0 += a1; b0 += b1; \
    a1 = __builtin_rotateleft32(a1, r); b1 = __builtin_rotateleft32(b1, r); \
    a1 ^= a0; b1 ^= b0;
#define TF4(p,q,rr,s) QR2(p) QR2(q) QR2(rr) QR2(s)
#define TF_FULL \
    TF4(13,15,26,6)   a0 += 42u;          a1 += 0x1BD11BF1u;  b0 += 42u;          b1 += 0x1BD11BF1u; \
    TF4(17,29,16,24)  a0 += 0x1BD11BF0u;  a1 += 2u;           b0 += 0x1BD11BF0u;  b1 += 2u; \
    TF4(13,15,26,6)                       a1 += 45u;                              b1 += 45u; \
    TF4(17,29,16,24)  a0 += 42u;          a1 += 0x1BD11BF4u;  b0 += 42u;          b1 += 0x1BD11BF4u; \
    TF4(13,15,26,6)   a0 += 0x1BD11BF0u;  a1 += 5u;

// 16 PRIVATE mask bits for this thread's own elements:
// rows qt*256 + w*16 + kg*4 + r (r=0..3), cols kt*64 + n*16 + lrow (n=0..3).
// bit index = n*4 + r. Chain a: bits 0..7 (n<2); chain b: bits 8..15 (n>=2, +32 cols).
#define MASK16(ktArg, dst) do { \
    u32 wm_ = 0u; \
    const u32 cb_ = ((u32)(bh * 2048 + qt * 256 + w * 16 + kg * 4) << 11) \
                  + (u32)(ktArg) * 64u + (u32)lrow + 42u; \
    _Pragma("unroll") \
    for (int j_ = 0; j_ < 8; ++j_) { \
        u32 a0 = 0u, a1 = cb_ + (u32)((j_ >> 2) * 16 + (j_ & 3) * 2048); \
        u32 b0 = 0u, b1 = a1 + 32u; \
        TF_FULL b1 += 5u; \
        wm_ |= ((a0 ^ a1) < 0xE6666600u) ? (1u << j_) : 0u; \
        wm_ |= ((b0 ^ b1) < 0xE6666600u) ? (1u << (j_ + 8)) : 0u; \
    } \
    (dst) = wm_; \
} while (0)

// NOTE: TF_FULL above ends with "a1 += 5u;" and the b-chain's final "b1 += 5u"
// is appended at the use site so the macro stays a single statement sequence —
// the executed per-chain op sequence is IDENTICAL to the verified R8/R15 code:
//   ...TF4(13,15,26,6) a0+=0x1BD11BF0; a1+=5; b0+=0x1BD11BF0; b1+=5;
// (b0's final inject is hoisted into TF_FULL's tail below.)
#undef TF_FULL
#define TF_FULL \
    TF4(13,15,26,6)   a0 += 42u;          a1 += 0x1BD11BF1u;  b0 += 42u;          b1 += 0x1BD11BF1u; \
    TF4(17,29,16,24)  a0 += 0x1BD11BF0u;  a1 += 2u;           b0 += 0x1BD11BF0u;  b1 += 2u; \
    TF4(13,15,26,6)                       a1 += 45u;                              b1 += 45u; \
    TF4(17,29,16,24)  a0 += 42u;          a1 += 0x1BD11BF4u;  b0 += 42u;          b1 += 0x1BD11BF4u; \
    TF4(13,15,26,6)   a0 += 0x1BD11BF0u;  a1 += 5u;           b0 += 0x1BD11BF0u;
#undef MASK16
#define MASK16(ktArg, dst) do { \
    u32 wm_ = 0u; \
    const u32 cb_ = ((u32)(bh * 2048 + qt * 256 + w * 16 + kg * 4) << 11) \
                  + (u32)(ktArg) * 64u + (u32)lrow + 42u; \
    _Pragma("unroll") \
    for (int j_ = 0; j_ < 8; ++j_) { \
        u32 a0 = 0u, a1 = cb_ + (u32)((j_ >> 2) * 16 + (j_ & 3) * 2048); \
        u32 b0 = 0u, b1 = a1 + 32u; \
        TF_FULL b1 += 5u; \
        wm_ |= ((a0 ^ a1) < 0xE6666600u) ? (1u << j_) : 0u; \
        wm_ |= ((b0 ^ b1) < 0xE6666600u) ? (1u << (j_ + 8)) : 0u; \
    } \
    (dst) = wm_; \
} while (0)

// ---------------- fused Q+K proj: out[f] = sum_e x[e]*W[f][e] + b[f], [b,h,s,e] ----------------
// blocks 0..511 -> Q, 512..1023 -> K (identical code path, pointer select)
__global__ __launch_bounds__(256) void proj_qk_kernel(
    const float* __restrict__ Xq, const float* __restrict__ Xk,
    const float* __restrict__ Wq, const float* __restrict__ Wk,
    const float* __restrict__ bq, const float* __restrict__ bk,
    f16* __restrict__ Qh, f16* __restrict__ Ql,
    f16* __restrict__ Kh, f16* __restrict__ Kl)
{
    __shared__ __align__(16) float Wl[64 * 68];
    __shared__ __align__(16) float Xl[128 * 68];
    const int t = threadIdx.x;
    const int isK = (int)(blockIdx.x >> 9);
    const float* X    = isK ? Xk : Xq;
    const float* W    = isK ? Wk : Wq;
    const float* bias = isK ? bk : bq;
    f16* Oh = isK ? Kh : Qh;
    f16* Ol = isK ? Kl : Ql;
    const int tb = (int)(blockIdx.x & 511) * 128;

    for (int c = t; c < 1024; c += 256) {
        int f = c >> 4, e4 = (c & 15) << 2;
        *(float4*)&Wl[f * 68 + e4] = *(const float4*)(W + f * 64 + e4);
    }
    for (int c = t; c < 2048; c += 256) {
        int tok = c >> 4, e4 = (c & 15) << 2;
        *(float4*)&Xl[tok * 68 + e4] = *(const float4*)(X + (size_t)(tb + tok) * 64 + e4);
    }
    __syncthreads();

    const int tx = t & 15;
    const int ty = t >> 4;
    const int f0 = ty * 4;

    float acc[8][4];
#pragma unroll
    for (int i = 0; i < 8; ++i)
#pragma unroll
        for (int j = 0; j < 4; ++j) acc[i][j] = bias[f0 + j];

    for (int e = 0; e < 64; e += 4) {
        float4 wv[4];
#pragma unroll
        for (int j = 0; j < 4; ++j) wv[j] = *(float4*)&Wl[(f0 + j) * 68 + e];
#pragma unroll
        for (int i = 0; i < 8; ++i) {
            float4 xv = *(float4*)&Xl[(tx + 16 * i) * 68 + e];
#pragma unroll
            for (int j = 0; j < 4; ++j)
                acc[i][j] += xv.x * wv[j].x + xv.y * wv[j].y + xv.z * wv[j].z + xv.w * wv[j].w;
        }
    }

#pragma unroll
    for (int i = 0; i < 8; ++i) {
        int tin = tb + tx + 16 * i;
        int h  = tin & 7;
        int bs = tin >> 3;
        int b  = bs >> 11;
        int s  = bs & 2047;
        size_t o = ((size_t)(b * 8 + h) * 2048 + s) * 64 + f0;
        f16x4 hv, lv;
#pragma unroll
        for (int j = 0; j < 4; ++j) {
            float a = acc[i][j];
            f16 hh = (f16)a;
            hv[j] = hh;
            lv[j] = (f16)(a - (float)hh);
        }
        *(f16x4*)(Oh + o) = hv;
        *(f16x4*)(Ol + o) = lv;
    }
}

// ---------------- proj_v: one (bh, 128-s chunk) per block; store [b,h,e,s] coalesced ----------------
__global__ __launch_bounds__(256) void proj_v_kernel(
    const float* __restrict__ X, const float* __restrict__ W,
    const float* __restrict__ bias,
    f16* __restrict__ Oh, f16* __restrict__ Ol)
{
    __shared__ __align__(16) float Wl[64 * 68];
    __shared__ __align__(16) float Xl[128 * 68];   // reused as Th/Tl after compute
    const int t = threadIdx.x;
    const int sc0 = blockIdx.x * 128;
    const int bh = blockIdx.y, b = bh >> 3, h = bh & 7;

    for (int c = t; c < 1024; c += 256) {
        int f = c >> 4, e4 = (c & 15) << 2;
        *(float4*)&Wl[f * 68 + e4] = *(const float4*)(W + f * 64 + e4);
    }
    for (int c = t; c < 2048; c += 256) {          // tokens of same (b,h): stride 8 in [B,S,H,E]
        int tok = c >> 4, e4 = (c & 15) << 2;
        size_t src = ((size_t)(b * 2048 + sc0 + tok) * 8 + h) * 64 + e4;
        *(float4*)&Xl[tok * 68 + e4] = *(const float4*)(X + src);
    }
    __syncthreads();

    const int tx = t & 15;
    const int ty = t >> 4;
    const int f0 = ty * 4;

    float acc[8][4];
#pragma unroll
    for (int i = 0; i < 8; ++i)
#pragma unroll
        for (int j = 0; j < 4; ++j) acc[i][j] = bias[f0 + j];

    for (int e = 0; e < 64; e += 4) {
        float4 wv[4];
#pragma unroll
        for (int j = 0; j < 4; ++j) wv[j] = *(float4*)&Wl[(f0 + j) * 68 + e];
#pragma unroll
        for (int i = 0; i < 8; ++i) {
            float4 xv = *(float4*)&Xl[(tx + 16 * i) * 68 + e];
#pragma unroll
            for (int j = 0; j < 4; ++j)
                acc[i][j] += xv.x * wv[j].x + xv.y * wv[j].y + xv.z * wv[j].z + xv.w * wv[j].w;
        }
    }
    __syncthreads();                               // done reading Xl -> reuse as transpose tile

    f16* Th = (f16*)Xl;            // [64 f][136 s]
    f16* Tl = Th + 64 * 136;
#pragma unroll
    for (int i = 0; i < 8; ++i) {
        int s = tx + 16 * i;
#pragma unroll
        for (int j = 0; j < 4; ++j) {
            float a = acc[i][j];
            f16 hh = (f16)a;
            Th[(f0 + j) * 136 + s] = hh;
            Tl[(f0 + j) * 136 + s] = (f16)(a - (float)hh);
        }
    }
    __syncthreads();

    for (int c = t; c < 1024; c += 256) {          // 64 e-rows x 128 s, uint4 = 8 f16
        int e = c >> 4, sc = (c & 15) << 3;
        size_t o = ((size_t)bh * 64 + e) * 2048 + sc0 + sc;
        *(uint4*)(Oh + o) = *(uint4*)&Th[e * 136 + sc];
        *(uint4*)(Ol + o) = *(uint4*)&Tl[e * 136 + sc];
    }
}

// identical score computation for both passes (bit-identical chain order per element)
#define COMPUTE_S(S, khp, klp) do { \
    _Pragma("unroll") for (int n = 0; n < 4; ++n) S[n] = f32x4v{0.f,0.f,0.f,0.f}; \
    _Pragma("unroll") for (int n = 0; n < 4; ++n) { \
        _Pragma("unroll") for (int ks = 0; ks < 2; ++ks) { \
            const int off_ = (n * 16 + lrow) * LDK + ks * 32 + kg * 8; \
            f16x8 bhf_ = *(const f16x8*)&(khp)[off_]; \
            f16x8 blf_ = *(const f16x8*)&(klp)[off_]; \
            S[n] = __builtin_amdgcn_mfma_f32_16x16x32_f16(qh[ks], bhf_, S[n], 0, 0, 0); \
            S[n] = __builtin_amdgcn_mfma_f32_16x16x32_f16(ql[ks], bhf_, S[n], 0, 0, 0); \
            S[n] = __builtin_amdgcn_mfma_f32_16x16x32_f16(qh[ks], blf_, S[n], 0, 0, 0); \
        } \
    } } while (0)

// grid (8, 32): x = 256-row Q tile, y = bh. 16 waves x 16 rows. 1 block/CU.
// MFMA 16x16x32 f16. A: A[m=lane&15][k=(lane>>4)*8+j]; B: B[k][n=lane&15];
// C: row=(lane>>4)*4+r, col=lane&15.
__global__ __launch_bounds__(1024, 4) void attn_kernel(
    const f16* __restrict__ Qh, const f16* __restrict__ Ql,
    const f16* __restrict__ Kh, const f16* __restrict__ Kl,
    const f16* __restrict__ Vth, const f16* __restrict__ Vtl,
    float* __restrict__ out)
{
    constexpr int LDK = 88;   // K/V f16 stride: 176 B rows (16B aligned)
    constexpr int PLD = 68;   // p_l f16 stride: 136 B rows (34 dw) -> conflict-free writes
    __shared__ __align__(16) f16 kh_l[2][64 * LDK];   // double-buffered
    __shared__ __align__(16) f16 kl_l[2][64 * LDK];
    __shared__ __align__(16) f16 vh_l[2][64 * LDK];   // [e][s]
    __shared__ __align__(16) f16 vl_l[2][64 * LDK];
    __shared__ __align__(16) f16 p_l[16][16 * PLD];   // per-wave P tile (16 rows)

    const int t = threadIdx.x;
    const int w = t >> 6;
    const int lane = t & 63;
    const int lrow = lane & 15;
    const int kg = lane >> 4;
    const int qt = blockIdx.x;
    const int bh = blockIdx.y;

    // staging role: threads 0..511 -> K, 512..1023 -> V. One uint4 pair each.
    const int sc  = t & 511;
    const int sx  = sc >> 3;            // K row / V e-row
    const int sc8 = (sc & 7) << 3;
    const bool isK = (t < 512);

    // persistent Q fragments (hi/lo), one 16-row m-tile per wave, 2 k-steps
    f16x8 qh[2], ql[2];
    {
        size_t rowg = (size_t)bh * 2048 + qt * 256 + w * 16 + lrow;
        const f16* ph = Qh + rowg * 64 + kg * 8;
        const f16* pl = Ql + rowg * 64 + kg * 8;
        qh[0] = *(const f16x8*)(ph);
        qh[1] = *(const f16x8*)(ph + 32);
        ql[0] = *(const f16x8*)(pl);
        ql[1] = *(const f16x8*)(pl + 32);
    }

    const size_t kbase = (size_t)bh * 2048 * 64;   // same footprint for K and Vt

    // ---- pass A: row sums l = sum exp(s - 8); K only, double-buffered ----
    float lsum[4] = {0.f, 0.f, 0.f, 0.f};
    if (isK) {      // prologue: stage kt=0 into buf 0
        size_t g = kbase + (size_t)(sx * 64) + sc8;
        uint4 h4 = *(const uint4*)(Kh + g);
        uint4 l4 = *(const uint4*)(Kl + g);
        *(uint4*)&kh_l[0][sx * LDK + sc8] = h4;
        *(uint4*)&kl_l[0][sx * LDK + sc8] = l4;
    }
    __syncthreads();

    for (int kt = 0; kt < 32; ++kt) {
        const int cur = kt & 1;
        uint4 sA, sB;
        if (isK && kt < 31) {           // issue next tile's loads early
            size_t g = kbase + (size_t)((kt + 1) * 64 + sx) * 64 + sc8;
            sA = *(const uint4*)(Kh + g);
            sB = *(const uint4*)(Kl + g);
        }
        f32x4v sfr[4];
        COMPUTE_S(sfr, kh_l[cur], kl_l[cur]);
#pragma unroll
        for (int n = 0; n < 4; ++n)
#pragma unroll
            for (int r = 0; r < 4; ++r)
                lsum[r] += __expf(fmaf(sfr[n][r], 0.125f, -8.0f));
        if (isK && kt < 31) {           // commit after compute
            *(uint4*)&kh_l[cur ^ 1][sx * LDK + sc8] = sA;
            *(uint4*)&kl_l[cur ^ 1][sx * LDK + sc8] = sB;
        }
        __syncthreads();                // single barrier per kt
    }

    float rsc[4];
#pragma unroll
    for (int r = 0; r < 4; ++r) {
        float v = lsum[r];
        v += __shfl_xor(v, 1);
        v += __shfl_xor(v, 2);
        v += __shfl_xor(v, 4);
        v += __shfl_xor(v, 8);
        rsc[r] = 1.0f / (0.9f * v);   // folds dropout 1/(1-p)
    }

    // ---- pass B: recompute s, exact p, PRIVATE threefry dropout, fp16 cast, PV ----
    f32x4v oacc[4];
#pragma unroll
    for (int fn = 0; fn < 4; ++fn) oacc[fn] = f32x4v{0.f, 0.f, 0.f, 0.f};

    {   // prologue: stage kt=0 (K and V) into buf 0
        if (isK) {
            size_t g = kbase + (size_t)(sx * 64) + sc8;
            uint4 h4 = *(const uint4*)(Kh + g);
            uint4 l4 = *(const uint4*)(Kl + g);
            *(uint4*)&kh_l[0][sx * LDK + sc8] = h4;
            *(uint4*)&kl_l[0][sx * LDK + sc8] = l4;
        } else {
            size_t g = kbase + (size_t)sx * 2048 + sc8;
            uint4 h4 = *(const uint4*)(Vth + g);
            uint4 l4 = *(const uint4*)(Vtl + g);
            *(uint4*)&vh_l[0][sx * LDK + sc8] = h4;
            *(uint4*)&vl_l[0][sx * LDK + sc8] = l4;
        }
    }
    __syncthreads();

    for (int kt = 0; kt < 32; ++kt) {
        const int cur = kt & 1;
        uint4 sA, sB;
        if (kt < 31) {                  // issue next tile's loads early
            if (isK) {
                size_t g = kbase + (size_t)((kt + 1) * 64 + sx) * 64 + sc8;
                sA = *(const uint4*)(Kh + g);
                sB = *(const uint4*)(Kl + g);
            } else {
                size_t g = kbase + (size_t)sx * 2048 + (kt + 1) * 64 + sc8;
                sA = *(const uint4*)(Vth + g);
                sB = *(const uint4*)(Vtl + g);
            }
        }

        u32 pm;
        MASK16(kt, pm);                 // thread-private threefry (pure VALU)

        f32x4v sfr[4];
        COMPUTE_S(sfr, kh_l[cur], kl_l[cur]);

#pragma unroll
        for (int n = 0; n < 4; ++n)
#pragma unroll
            for (int r = 0; r < 4; ++r) {
                float e = __expf(fmaf(sfr[n][r], 0.125f, -8.0f));
                float p = e * rsc[r];
                if (!((pm >> (n * 4 + r)) & 1u)) p = 0.0f;
                p_l[w][(kg * 4 + r) * PLD + n * 16 + lrow] = (f16)p;  // RTNE = astype(f16)
            }

        // PV: out += P(16f exact) * (Vh + Vl)   (wave-private p_l: no barrier)
        // P-frag read as 2x ds_read_b64 (rows 8B-aligned at PLD=68)
#pragma unroll
        for (int ks = 0; ks < 2; ++ks) {
            const int pbase = lrow * PLD + ks * 32 + kg * 8;
            f16x4 plo = *(const f16x4*)&p_l[w][pbase];
            f16x4 phi = *(const f16x4*)&p_l[w][pbase + 4];
            f16x8 pa0;
#pragma unroll
            for (int z = 0; z < 4; ++z) { pa0[z] = plo[z]; pa0[z + 4] = phi[z]; }
#pragma unroll
            for (int fn = 0; fn < 4; ++fn) {
                const int voff = (fn * 16 + lrow) * LDK + ks * 32 + kg * 8;
                f16x8 vhf = *(const f16x8*)&vh_l[cur][voff];
                f16x8 vlf = *(const f16x8*)&vl_l[cur][voff];
                oacc[fn] = __builtin_amdgcn_mfma_f32_16x16x32_f16(pa0, vhf, oacc[fn], 0, 0, 0);
                oacc[fn] = __builtin_amdgcn_mfma_f32_16x16x32_f16(pa0, vlf, oacc[fn], 0, 0, 0);
            }
        }

        if (kt < 31) {                  // commit after compute
            if (isK) {
                *(uint4*)&kh_l[cur ^ 1][sx * LDK + sc8] = sA;
                *(uint4*)&kl_l[cur ^ 1][sx * LDK + sc8] = sB;
            } else {
                *(uint4*)&vh_l[cur ^ 1][sx * LDK + sc8] = sA;
                *(uint4*)&vl_l[cur ^ 1][sx * LDK + sc8] = sB;
            }
        }
        __syncthreads();                // single barrier per kt
    }

    // epilogue: out [b,h,s,e] fp32
#pragma unroll
    for (int fn = 0; fn < 4; ++fn)
#pragma unroll
        for (int r = 0; r < 4; ++r) {
            int row = qt * 256 + w * 16 + kg * 4 + r;
            out[((size_t)bh * 2048 + row) * 64 + fn * 16 + lrow] = oacc[fn][r];
        }
}

extern "C" void kernel_launch(void* const* d_in, const int* in_sizes, int n_in,
                              void* d_out, int out_size, void* d_ws, size_t ws_size,
                              hipStream_t stream) {
    (void)in_sizes; (void)n_in; (void)out_size; (void)ws_size;
    const float* query = (const float*)d_in[0];
    const float* key_  = (const float*)d_in[1];
    const float* value = (const float*)d_in[2];
    const float* Wq = (const float*)d_in[3];
    const float* bq = (const float*)d_in[4];
    const float* Wk = (const float*)d_in[5];
    const float* bk = (const float*)d_in[6];
    const float* Wv = (const float*)d_in[7];
    const float* bv = (const float*)d_in[8];

    char* ws = (char*)d_ws;                 // needs 48 MiB
    f16* Qh  = (f16*)(ws);
    f16* Ql  = (f16*)(ws + 8388608);
    f16* Kh  = (f16*)(ws + 16777216);
    f16* Kl  = (f16*)(ws + 25165824);
    f16* Vth = (f16*)(ws + 33554432);
    f16* Vtl = (f16*)(ws + 41943040);

    proj_qk_kernel<<<1024, 256, 0, stream>>>(query, key_, Wq, Wk, bq, bk, Qh, Ql, Kh, Kl);
    proj_v_kernel<<<dim3(16, 32), 256, 0, stream>>>(value, Wv, bv, Vth, Vtl);
    attn_kernel<<<dim3(8, 32), 1024, 0, stream>>>(Qh, Ql, Kh, Kl, Vth, Vtl, (float*)d_out);
}